// Round 12
// baseline (1346.582 us; speedup 1.0000x reference)
//
#include <hip/hip_runtime.h>
#include <hip/hip_bf16.h>

#define B_ 32
#define L_ 512
#define D_ 768
#define DFF_ 3072
#define NL_ 2
#define TOPK_ 6
#define CMID_ 384
#define CLEN_ 510
#define PLEN_ 255
#define LATENT_ 32
#define NCELLS_ 2034
#define NROWS_ (B_*L_)
#define ND_ ((size_t)B_*L_*D_)

typedef unsigned short ushort_t;
typedef __attribute__((ext_vector_type(8))) short short8;
typedef __attribute__((ext_vector_type(4))) float f32x4;

typedef const __attribute__((address_space(1))) unsigned int* gp1;
typedef __attribute__((address_space(3))) unsigned int* lp3;

static __device__ __forceinline__ void gload16(const ushort_t* g, ushort_t* l) {
  __builtin_amdgcn_global_load_lds((gp1)g, (lp3)l, 16, 0, 0);
}

static __device__ __forceinline__ float geluf(float x) {
  return 0.5f * x * (1.f + erff(x * 0.70710678118654752440f));
}
static __device__ __forceinline__ float eluf(float x) {
  return x > 0.f ? x : expm1f(x);
}
static __device__ __forceinline__ ushort_t bf16rn(float f) {
  unsigned u = __builtin_bit_cast(unsigned, f);
  u = u + 0x7FFFu + ((u >> 16) & 1u);
  return (ushort_t)(u >> 16);
}
static __device__ __forceinline__ float bf16tof(ushort_t s) {
  unsigned u = ((unsigned)s) << 16;
  return __builtin_bit_cast(float, u);
}
static __device__ __forceinline__ f32x4 mfma16(short8 a, short8 b, f32x4 c) {
  return __builtin_amdgcn_mfma_f32_16x16x32_bf16(a, b, c, 0, 0, 0);
}

// ---------------- weight conversion ----------------
__global__ void wsplit(const float* __restrict__ w, ushort_t* __restrict__ hi,
                       ushort_t* __restrict__ lo, size_t n) {
  size_t stride = (size_t)gridDim.x * blockDim.x;
  for (size_t i = (size_t)blockIdx.x * blockDim.x + threadIdx.x; i < n; i += stride) {
    float v = w[i];
    ushort_t h = bf16rn(v);
    hi[i] = h;
    if (lo) lo[i] = bf16rn(v - bf16tof(h));
  }
}

// batched transpose+split over 3 matrices x NL layers (z = mat*NL + layer)
__global__ __launch_bounds__(256) void tsplit3(const float* __restrict__ w0, const float* __restrict__ w1,
                                               const float* __restrict__ w2,
                                               ushort_t* __restrict__ h0, ushort_t* __restrict__ l0p,
                                               ushort_t* __restrict__ h1, ushort_t* __restrict__ l1p,
                                               ushort_t* __restrict__ h2, ushort_t* __restrict__ l2p) {
  __shared__ float tile[32][33];
  int z = blockIdx.z;
  int m = z / NL_, l = z % NL_;
  const float* in = (m == 0) ? w0 : (m == 1 ? w1 : w2);
  ushort_t* hiT = (m == 0) ? h0 : (m == 1 ? h1 : h2);
  ushort_t* loT = (m == 0) ? l0p : (m == 1 ? l1p : l2p);
  size_t off = (size_t)l * D_ * D_;
  int bx = blockIdx.x * 32, by = blockIdx.y * 32;
  int tx = threadIdx.x & 31, ty = threadIdx.x >> 5;
#pragma unroll
  for (int i = 0; i < 32; i += 8)
    tile[ty + i][tx] = in[off + (size_t)(by + ty + i) * D_ + bx + tx];
  __syncthreads();
#pragma unroll
  for (int i = 0; i < 32; i += 8) {
    float v = tile[tx][ty + i];
    ushort_t h = bf16rn(v);
    size_t o = off + (size_t)(bx + ty + i) * D_ + by + tx;
    hiT[o] = h;
    loT[o] = bf16rn(v - bf16tof(h));
  }
}

// bvo[l,a] = bo[l,a] + sum_j Wo[l,a,j]*bv[l,j]   (batched over layers)
__global__ void bvo_k(const float* __restrict__ wo, const float* __restrict__ bv,
                      const float* __restrict__ bo, float* __restrict__ bvo) {
  int gid = blockIdx.x * 256 + threadIdx.x;
  if (gid >= NL_ * D_) return;
  int l = gid / D_, a = gid % D_;
  const float* w = wo + (size_t)l * D_ * D_ + (size_t)a * D_;
  const float* b = bv + l * D_;
  float s = bo[gid];
  for (int j = 0; j < D_; j++) s = fmaf(w[j], b[j], s);
  bvo[gid] = s;
}

// conv weight repack+convert: wt[o, j*768+i] = bf16(w[o, i, j])
__global__ void conv_w_repack(const float* __restrict__ w, ushort_t* __restrict__ wt) {
  int gid = blockIdx.x * blockDim.x + threadIdx.x;
  if (gid >= CMID_ * 3 * D_) return;
  int o = gid / (3 * D_);
  int k = gid % (3 * D_);
  int j = k / D_, i = k % D_;
  wt[gid] = bf16rn(w[((size_t)o * D_ + i) * 3 + j]);
}

// ---------------- fused embeddings + LN -> bf16 hi/lo planes only ----------------
__global__ __launch_bounds__(256) void embed_ln(const int* __restrict__ ids, const float* __restrict__ we,
                                                const float* __restrict__ pe, const float* __restrict__ te,
                                                const float* __restrict__ g, const float* __restrict__ bta,
                                                ushort_t* __restrict__ xh, ushort_t* __restrict__ xl) {
  int row = blockIdx.x;
  int tid = threadIdx.x;
  int t = row & (L_ - 1);
  int id = ids[row];
  float v[3];
#pragma unroll
  for (int dd = 0; dd < 3; dd++) {
    int c = tid + dd * 256;
    v[dd] = we[(size_t)id * D_ + c] + pe[(size_t)t * D_ + c] + te[c];
  }
  float s = v[0] + v[1] + v[2];
  float sq = v[0]*v[0] + v[1]*v[1] + v[2]*v[2];
  __shared__ float rs[256], rq[256];
  rs[tid] = s; rq[tid] = sq;
  __syncthreads();
  for (int st = 128; st > 0; st >>= 1) {
    if (tid < st) { rs[tid] += rs[tid + st]; rq[tid] += rq[tid + st]; }
    __syncthreads();
  }
  __shared__ float smu, ssc;
  if (tid == 0) {
    float mu = rs[0] * (1.f / D_);
    float var = fmaxf(rq[0] * (1.f / D_) - mu * mu, 0.f);
    smu = mu; ssc = rsqrtf(var + 1e-12f);
  }
  __syncthreads();
  float mu = smu, sc = ssc;
#pragma unroll
  for (int dd = 0; dd < 3; dd++) {
    int c = tid + dd * 256;
    size_t o = (size_t)row * D_ + c;
    float ov = (v[dd] - mu) * sc * g[c] + bta[c];
    ushort_t h = bf16rn(ov);
    xh[o] = h;
    xl[o] = bf16rn(ov - bf16tof(h));
  }
}

// ---------------- LayerNorm (head) from planes ----------------
__global__ __launch_bounds__(256) void ln_pl(const ushort_t* __restrict__ xh, const ushort_t* __restrict__ xl,
                                             float* __restrict__ out,
                                             const float* __restrict__ g, const float* __restrict__ bta,
                                             float eps) {
  int row = blockIdx.x;
  int tid = threadIdx.x;
  size_t base = (size_t)row * D_;
  float v[3];
#pragma unroll
  for (int dd = 0; dd < 3; dd++) {
    size_t o = base + tid + dd * 256;
    v[dd] = bf16tof(xh[o]) + bf16tof(xl[o]);
  }
  float s = v[0] + v[1] + v[2];
  float sq = v[0]*v[0] + v[1]*v[1] + v[2]*v[2];
  __shared__ float rs[256], rq[256];
  rs[tid] = s; rq[tid] = sq;
  __syncthreads();
  for (int st = 128; st > 0; st >>= 1) {
    if (tid < st) { rs[tid] += rs[tid + st]; rq[tid] += rq[tid + st]; }
    __syncthreads();
  }
  __shared__ float smu, ssc;
  if (tid == 0) {
    float mu = rs[0] * (1.f / D_);
    float var = fmaxf(rq[0] * (1.f / D_) - mu * mu, 0.f);
    smu = mu; ssc = rsqrtf(var + eps);
  }
  __syncthreads();
  float mu = smu, sc = ssc;
  float* o = out + base;
#pragma unroll
  for (int dd = 0; dd < 3; dd++) {
    int c = tid + dd * 256;
    o[c] = (v[dd] - mu) * sc * g[c] + bta[c];
  }
}

// ---------------- MFMA GEMM (128^2, 2-barrier), bf16-plane inputs -------------
// The proven structure (~600 TF on FFN shapes, 0 bank conflicts).
// EPI: 0 = fp32 (+plane residual), 1 = bf16, 2 = bf16 hi+lo, 3 = diag partials, 4 = conv head.
template<int ACT, bool SPLIT, int EPI>
__global__ __launch_bounds__(256) void gemm_bf16(
    const ushort_t* __restrict__ Ah, const ushort_t* __restrict__ Al,
    const ushort_t* __restrict__ Wh, const ushort_t* __restrict__ Wl,
    const float* __restrict__ bias,
    const ushort_t* __restrict__ ResH, const ushort_t* __restrict__ ResL,
    void* __restrict__ C0, void* __restrict__ C1,
    const float* __restrict__ bn_m, const float* __restrict__ bn_v,
    const float* __restrict__ bn_g, const float* __restrict__ bn_b,
    int O, int K, int lda,
    long long sA, long long sW, long long sC,
    int nbx, int nby) {
  constexpr int NP = SPLIT ? 2 : 1;
  __shared__ __align__(16) ushort_t AsH[NP][128 * 64];
  __shared__ __align__(16) ushort_t WsH[NP][128 * 64];
  __shared__ float dsum[EPI == 3 ? 512 : 1];

  int nwg = gridDim.x;
  int wg = blockIdx.x;
  {
    int qq = nwg >> 3, rr = nwg & 7;
    int xcd = wg & 7, idx = wg >> 3;
    wg = (xcd < rr ? xcd * (qq + 1) : rr * (qq + 1) + (xcd - rr) * qq) + idx;
  }
  int per_b = nbx * nby;
  int bz = wg / per_b;
  int rem = wg - bz * per_b;
  int gsz = nbx * 8;
  int grp = rem / gsz;
  int ing = rem - grp * gsz;
  int by0 = grp * 8;
  int gmx = min(8, nby - by0);
  int by = by0 + (ing % gmx);
  int bx = ing / gmx;

  const ushort_t* Ahb = Ah + (size_t)bz * sA;
  const ushort_t* Alb = SPLIT ? (Al + (size_t)bz * sA) : nullptr;
  const ushort_t* Whb = Wh + (size_t)bz * sW;
  const ushort_t* Wlb = SPLIT ? (Wl + (size_t)bz * sW) : nullptr;

  int m0 = by * 128, o0 = bx * 128;
  int tid = threadIdx.x;
  int wave = tid >> 6, lane = tid & 63;
  int wm = (wave >> 1) * 64, wn = (wave & 1) * 64;
  int lcol = lane & 15, lk = lane >> 4;

  if (EPI == 3) {
    for (int s = tid; s < 512; s += 256) dsum[s] = 0.f;
  }

  f32x4 acc[4][4] = {};

  int r8 = lane >> 3;
  int kc = (((lane & 7) ^ r8) << 3);

  const ushort_t *gA[4], *gW[4], *gAl[4], *gWl[4];
#pragma unroll
  for (int i = 0; i < 4; i++) {
    int ch = wave * 4 + i;
    int row = ch * 8 + r8;
    size_t oa = (size_t)(m0 + row) * lda + kc;
    size_t ow = (size_t)(o0 + row) * K + kc;
    gA[i] = Ahb + oa; gW[i] = Whb + ow;
    if (SPLIT) { gAl[i] = Alb + oa; gWl[i] = Wlb + ow; }
  }

  for (int k0 = 0; k0 < K; k0 += 64) {
#pragma unroll
    for (int i = 0; i < 4; i++) {
      int ch = wave * 4 + i;
      gload16(gA[i], &AsH[0][ch * 512]); gA[i] += 64;
      gload16(gW[i], &WsH[0][ch * 512]); gW[i] += 64;
      if (SPLIT) {
        gload16(gAl[i], &AsH[1][ch * 512]); gAl[i] += 64;
        gload16(gWl[i], &WsH[1][ch * 512]); gWl[i] += 64;
      }
    }
    __syncthreads();
#pragma unroll
    for (int kk = 0; kk < 2; kk++) {
      int c = kk * 4 + lk;
      short8 ah[4], bh[4], al[4], bl[4];
#pragma unroll
      for (int i = 0; i < 4; i++) {
        int r = wm + i * 16 + lcol;
        int so = r * 64 + ((c ^ (r & 7)) << 3);
        ah[i] = *(const short8*)&AsH[0][so];
        if (SPLIT) al[i] = *(const short8*)&AsH[1][so];
      }
#pragma unroll
      for (int j = 0; j < 4; j++) {
        int r = wn + j * 16 + lcol;
        int so = r * 64 + ((c ^ (r & 7)) << 3);
        bh[j] = *(const short8*)&WsH[0][so];
        if (SPLIT) bl[j] = *(const short8*)&WsH[1][so];
      }
#pragma unroll
      for (int i = 0; i < 4; i++)
#pragma unroll
        for (int j = 0; j < 4; j++) {
          if (SPLIT) {
            acc[i][j] = mfma16(ah[i], bl[j], acc[i][j]);
            acc[i][j] = mfma16(al[i], bh[j], acc[i][j]);
          }
          acc[i][j] = mfma16(ah[i], bh[j], acc[i][j]);
        }
    }
    __syncthreads();
  }

  if (EPI == 3) {
    float pre[7][4] = {};
#pragma unroll
    for (int i = 0; i < 4; i++)
#pragma unroll
      for (int j = 0; j < 4; j++)
#pragma unroll
        for (int r = 0; r < 4; r++)
          pre[i - j + 3][r] += acc[i][j][r];
    int base = (m0 + wm + lk * 4) - (o0 + wn + lcol);
#pragma unroll
    for (int g = 0; g < 7; g++)
#pragma unroll
      for (int r = 0; r < 4; r++)
        atomicAdd(&dsum[(base + 16 * (g - 3) + r) & (L_ - 1)], pre[g][r]);
    __syncthreads();
    float* mvp = (float*)C0;
    int blk = by * nbx + bx;
    for (int s = tid; s < 512; s += 256)
      mvp[((size_t)bz * 16 + blk) * 512 + s] = dsum[s] * (1.f / D_);
  } else if (EPI == 4) {
#pragma unroll
    for (int j = 0; j < 4; j++) {
      int col = o0 + wn + j * 16 + lcol;
      float cbias = bias[col];
      float sc = rsqrtf(bn_v[col] + 1e-5f) * bn_g[col];
      float shf = bn_b[col] - bn_m[col] * sc;
#pragma unroll
      for (int i = 0; i < 4; i++) {
        int rowb = m0 + wm + i * 16 + lk * 4;
        int t = rowb & (L_ - 1);
        int b = rowb >> 9;
#pragma unroll
        for (int p = 0; p < 2; p++) {
          int tt = t + p * 2;
          if (tt >= CLEN_) continue;
          float v0 = eluf((acc[i][j][p * 2]     + cbias) * sc + shf);
          float v1 = eluf((acc[i][j][p * 2 + 1] + cbias) * sc + shf);
          ((float*)C0)[((size_t)b * CMID_ + col) * PLEN_ + (tt >> 1)] = fmaxf(v0, v1);
        }
      }
    }
  } else {
#pragma unroll
    for (int i = 0; i < 4; i++)
#pragma unroll
      for (int j = 0; j < 4; j++) {
        int col = o0 + wn + j * 16 + lcol;
        float bv = bias ? bias[col] : 0.f;
        int rowb = m0 + wm + i * 16 + lk * 4;
#pragma unroll
        for (int r = 0; r < 4; r++) {
          float v = acc[i][j][r] + bv;
          if (ACT == 1) v = geluf(v);
          size_t off = (size_t)bz * sC + (size_t)(rowb + r) * O + col;
          if (EPI == 0) {
            if (ResH) v += bf16tof(ResH[off]) + bf16tof(ResL[off]);
            ((float*)C0)[off] = v;
          }
          if (EPI == 1) ((ushort_t*)C0)[off] = bf16rn(v);
          if (EPI == 2) {
            ushort_t h = bf16rn(v);
            ((ushort_t*)C0)[off] = h;
            ((ushort_t*)C1)[off] = bf16rn(v - bf16tof(h));
          }
        }
      }
  }
}

// ---------------- top-k(6) + softmax over delays (sums 16 partials) ----------------
__global__ __launch_bounds__(256) void topk_softmax(const float* __restrict__ mvp,
                                                    float* __restrict__ wout, int* __restrict__ dout) {
  int b = blockIdx.x, tid = threadIdx.x;
  __shared__ float vals[L_];
  __shared__ float rv[256];
  __shared__ int ri[256];
  __shared__ float wsel[TOPK_];
  __shared__ int dsel[TOPK_];
  float s0 = 0.f, s1 = 0.f;
  for (int p = 0; p < 16; p++) {
    const float* pp = mvp + ((size_t)b * 16 + p) * L_;
    s0 += pp[tid]; s1 += pp[tid + 256];
  }
  vals[tid] = s0; vals[tid + 256] = s1;
  for (int kk = 0; kk < TOPK_; kk++) {
    __syncthreads();
    float v0 = vals[tid], v1 = vals[tid + 256];
    float bvv = v0; int bi = tid;
    if (v1 > v0) { bvv = v1; bi = tid + 256; }
    rv[tid] = bvv; ri[tid] = bi;
    __syncthreads();
    for (int st = 128; st > 0; st >>= 1) {
      if (tid < st) {
        float ov = rv[tid + st]; int oi = ri[tid + st];
        if (ov > rv[tid] || (ov == rv[tid] && oi < ri[tid])) { rv[tid] = ov; ri[tid] = oi; }
      }
      __syncthreads();
    }
    if (tid == 0) { wsel[kk] = rv[0]; dsel[kk] = ri[0]; vals[ri[0]] = -INFINITY; }
  }
  __syncthreads();
  if (tid == 0) {
    float mx = wsel[0];
    for (int i = 1; i < TOPK_; i++) mx = fmaxf(mx, wsel[i]);
    float e[TOPK_]; float sum = 0.f;
    for (int i = 0; i < TOPK_; i++) { e[i] = expf(wsel[i] - mx); sum += e[i]; }
    for (int i = 0; i < TOPK_; i++) { wout[b * TOPK_ + i] = e[i] / sum; dout[b * TOPK_ + i] = dsel[i]; }
  }
}

// fused agg + decomp: Y(t) = sum_k w_k*P[b,(t+dly_k)%L,d] + (xh+xl)[b,t,d];
// out = Y - movavg25(Y), written as bf16 hi/lo planes to DISTINCT buffers
// (oh/ol must not alias xh/xl or P — round-11 ran it in place and raced).
__global__ void agg_decomp(const ushort_t* __restrict__ P, const float* __restrict__ w,
                           const int* __restrict__ dly,
                           const ushort_t* __restrict__ xh, const ushort_t* __restrict__ xl,
                           ushort_t* __restrict__ oh, ushort_t* __restrict__ ol) {
  int gid = blockIdx.x * blockDim.x + threadIdx.x;   // B*8*D
  if (gid >= B_ * 8 * D_) return;
  int d = gid % D_;
  int chunk = (gid / D_) & 7;
  int b = gid / (D_ * 8);
  size_t base = (size_t)b * L_ * D_ + d;
  float ww[TOPK_]; int dk[TOPK_];
#pragma unroll
  for (int k = 0; k < TOPK_; k++) { ww[k] = w[b * TOPK_ + k]; dk[k] = dly[b * TOPK_ + k]; }
  auto Yat = [&](int t) -> float {
    int tc = t < 0 ? 0 : (t > L_ - 1 ? L_ - 1 : t);
    size_t o = base + (size_t)tc * D_;
    float s = bf16tof(xh[o]) + bf16tof(xl[o]);
#pragma unroll
    for (int k = 0; k < TOPK_; k++)
      s = fmaf(ww[k], bf16tof(P[base + (size_t)((tc + dk[k]) & (L_ - 1)) * D_]), s);
    return s;
  };
  int t0 = chunk * 64;
  float wsum = 0.f;
  for (int u = t0 - 12; u <= t0 + 12; u++) wsum += Yat(u);
  for (int t = t0; t < t0 + 64; t++) {
    float v = Yat(t) - wsum * (1.f / 25.f);
    size_t o = base + (size_t)t * D_;
    ushort_t h = bf16rn(v);
    oh[o] = h;
    ol[o] = bf16rn(v - bf16tof(h));
    wsum += Yat(t + 13) - Yat(t - 12);
  }
}

// race-free decomp (FFN path): reads fp32 sum S, writes bf16 hi/lo planes
__global__ void decomp_pl(const float* __restrict__ s,
                          ushort_t* __restrict__ xh, ushort_t* __restrict__ xl) {
  int gid = blockIdx.x * blockDim.x + threadIdx.x;   // B*8*D
  if (gid >= B_ * 8 * D_) return;
  int d = gid % D_;
  int chunk = (gid / D_) & 7;
  int b = gid / (D_ * 8);
  size_t base = (size_t)b * L_ * D_ + d;
  int t0 = chunk * 64;
  float wsum = 0.f;
  for (int u = t0 - 12; u <= t0 + 12; u++) {
    int uc = u < 0 ? 0 : (u > L_ - 1 ? L_ - 1 : u);
    wsum += s[base + (size_t)uc * D_];
  }
  for (int t = t0; t < t0 + 64; t++) {
    size_t o = base + (size_t)t * D_;
    float v = s[o] - wsum * (1.f / 25.f);
    ushort_t h = bf16rn(v);
    xh[o] = h;
    xl[o] = bf16rn(v - bf16tof(h));
    int ua = t + 13 > L_ - 1 ? L_ - 1 : t + 13;
    int ur = t - 12 < 0 ? 0 : t - 12;
    wsum += s[base + (size_t)ua * D_] - s[base + (size_t)ur * D_];
  }
}

// x[b,:,d] -= mean_t; write bf16 plane only
__global__ void colmean_bf16(const float* __restrict__ x, ushort_t* __restrict__ sh) {
  int gid = blockIdx.x * blockDim.x + threadIdx.x;   // B*D
  if (gid >= B_ * D_) return;
  int d = gid % D_, b = gid / D_;
  const float* col = x + (size_t)b * L_ * D_ + d;
  ushort_t* oc = sh + (size_t)b * L_ * D_ + d;
  float s = 0.f;
  for (int t = 0; t < L_; t++) s += col[(size_t)t * D_];
  float mu = s * (1.f / L_);
  for (int t = 0; t < L_; t++) oc[(size_t)t * D_] = bf16rn(col[(size_t)t * D_] - mu);
}

__global__ __launch_bounds__(256) void lin1_k(const float* __restrict__ f, const float* __restrict__ w,
                                              const float* __restrict__ bias, float* __restrict__ out) {
  int o = blockIdx.x, b = blockIdx.y;
  int tid = threadIdx.x;
  const float4* fr = (const float4*)(f + (size_t)b * (CMID_ * PLEN_));
  const float4* wr = (const float4*)(w + (size_t)o * (CMID_ * PLEN_));
  const int n4 = CMID_ * PLEN_ / 4;
  float s = 0.f;
  for (int i = tid; i < n4; i += 256) {
    float4 a = fr[i], ww = wr[i];
    s += a.x * ww.x + a.y * ww.y + a.z * ww.z + a.w * ww.w;
  }
  __shared__ float red[256];
  red[tid] = s;
  __syncthreads();
  for (int st = 128; st > 0; st >>= 1) {
    if (tid < st) red[tid] += red[tid + st];
    __syncthreads();
  }
  if (tid == 0) out[b * LATENT_ + o] = red[0] + bias[o];
}

__global__ void ln_elu(const float* __restrict__ hp, const float* __restrict__ g,
                       const float* __restrict__ bb, float* __restrict__ h) {
  int b = blockIdx.x;
  int tid = threadIdx.x;   // 64
  __shared__ float v[LATENT_];
  __shared__ float mu_s, sc_s;
  if (tid < LATENT_) v[tid] = hp[b * LATENT_ + tid];
  __syncthreads();
  if (tid == 0) {
    float s = 0.f, sq = 0.f;
    for (int i = 0; i < LATENT_; i++) { s += v[i]; sq += v[i] * v[i]; }
    float mu = s * (1.f / LATENT_);
    float var = fmaxf(sq * (1.f / LATENT_) - mu * mu, 0.f);
    mu_s = mu; sc_s = rsqrtf(var + 1e-5f);
  }
  __syncthreads();
  if (tid < LATENT_) h[b * LATENT_ + tid] = eluf((v[tid] - mu_s) * sc_s * g[tid] + bb[tid]);
}

__global__ void lin2_sig(const float* __restrict__ h, const float* __restrict__ w,
                         const float* __restrict__ bias, float* __restrict__ out) {
  int gid = blockIdx.x * blockDim.x + threadIdx.x;
  if (gid >= B_ * NCELLS_) return;
  int b = gid / NCELLS_, c = gid % NCELLS_;
  const float* hr = h + b * LATENT_;
  const float* wr = w + (size_t)c * LATENT_;
  float s = bias[c];
  for (int j = 0; j < LATENT_; j++) s = fmaf(hr[j], wr[j], s);
  out[gid] = 1.f / (1.f + expf(-s));
}

extern "C" void kernel_launch(void* const* d_in, const int* in_sizes, int n_in,
                              void* d_out, int out_size, void* d_ws, size_t ws_size,
                              hipStream_t stream) {
  const int*   ids  = (const int*)  d_in[0];
  const float* we   = (const float*)d_in[1];
  const float* pe   = (const float*)d_in[2];
  const float* te   = (const float*)d_in[3];
  const float* elng = (const float*)d_in[4];
  const float* elnb = (const float*)d_in[5];
  const float* Wq   = (const float*)d_in[6];
  const float* bq   = (const float*)d_in[7];   (void)bq;  // drops out (shift-invariance)
  const float* Wk   = (const float*)d_in[8];
  const float* bk   = (const float*)d_in[9];   (void)bk;  // drops out
  const float* Wv   = (const float*)d_in[10];
  const float* bv   = (const float*)d_in[11];
  const float* Wo   = (const float*)d_in[12];
  const float* bo   = (const float*)d_in[13];
  const float* Wc1  = (const float*)d_in[14];
  const float* bc1  = (const float*)d_in[15];
  const float* Wc2  = (const float*)d_in[16];
  const float* bc2  = (const float*)d_in[17];
  const float* ng   = (const float*)d_in[18];
  const float* nb   = (const float*)d_in[19];
  const float* cw   = (const float*)d_in[20];
  const float* cb   = (const float*)d_in[21];
  const float* bng  = (const float*)d_in[22];
  const float* bnb  = (const float*)d_in[23];
  const float* bnm  = (const float*)d_in[24];
  const float* bnv  = (const float*)d_in[25];
  const float* l1w  = (const float*)d_in[26];
  const float* l1b  = (const float*)d_in[27];
  const float* l2g  = (const float*)d_in[28];
  const float* l2b  = (const float*)d_in[29];
  const float* l2w  = (const float*)d_in[30];
  const float* l2bi = (const float*)d_in[31];
  float* out = (float*)d_out;

  // ---- workspace carve-up ----
  char* wp = (char*)d_ws;
  auto alloc = [&](size_t bytes) { char* p = wp; wp += (bytes + 255) & ~(size_t)255; return p; };
  ushort_t* Xh  = (ushort_t*)alloc(ND_ * 2);
  ushort_t* Xl  = (ushort_t*)alloc(ND_ * 2);
  ushort_t* X2h = (ushort_t*)alloc(ND_ * 2);   // attn-decomp output planes (ping-pong)
  ushort_t* X2l = (ushort_t*)alloc(ND_ * 2);
  ushort_t* R1  = (ushort_t*)alloc(ND_ * 2 * 4);   // XMh|XMl ; precompute scratch ; Gh ; F(head)
  char*     PvB = (char*)    alloc(ND_ * 4);       // P bf16 ; head: LN fp32 output
  float*    Y   = (float*)   alloc(ND_ * 4);       // FFN residual sums (fp32)
  float*    MVP = (float*)   alloc((size_t)B_ * 16 * L_ * 4);
  float*    WT  = (float*)   alloc(B_ * TOPK_ * 4);
  int*      DT  = (int*)     alloc(B_ * TOPK_ * 4);
  float*    HP  = (float*)   alloc(B_ * LATENT_ * 4);
  float*    HH  = (float*)   alloc(B_ * LATENT_ * 4);
  const size_t DD = (size_t)D_ * D_, DF = (size_t)DFF_ * D_;
  // persistent fused-weight block: C-hi = [MTh l0,l1 | WvoH l0,l1], C-lo = [MTl l0,l1 | (junk)]
  ushort_t* PCC_h = (ushort_t*)alloc(4 * DD * 2);
  ushort_t* PCC_l = (ushort_t*)alloc(4 * DD * 2);
  float*    BVO  = (float*)   alloc(NL_ * D_ * 4);   // Wo*bv + bo
  ushort_t* W1H  = (ushort_t*)alloc(NL_ * DF * 2);
  ushort_t* W2H  = (ushort_t*)alloc(NL_ * DF * 2);
  ushort_t* WTC  = (ushort_t*)alloc((size_t)CMID_ * 3 * D_ * 2);

  ushort_t* MTh  = PCC_h;                // + l*DD
  ushort_t* MTl  = PCC_l;
  ushort_t* WvoH = PCC_h + NL_ * DD;

  ushort_t* XMh = R1;
  ushort_t* XMl = R1 + ND_;
  ushort_t* Gh  = R1;          // FFN mid, overlays whole R1
  float*    F   = (float*)R1;  // head pooled features
  ushort_t* Pb  = (ushort_t*)PvB;   // P bf16
  float*    LNo = (float*)PvB;      // head LN output (P dead)
  ushort_t* Sh  = X2h;              // head bf16 plane (X2 planes dead at head)

  // precompute scratch planes (overlay R1 — dead until the layer loop).
  ushort_t* SC = R1;
  ushort_t* PCA_h = SC;                   // 4*DD
  ushort_t* PCA_l = SC + 4 * DD;
  ushort_t* PCW_h = SC + 8 * DD;
  ushort_t* PCW_l = SC + 12 * DD;
  ushort_t* WkTh = PCA_h;                 ushort_t* WkTl = PCA_l;
  ushort_t* WoH  = PCA_h + NL_ * DD;      ushort_t* WoL  = PCA_l + NL_ * DD;
  ushort_t* WqTh = PCW_h;                 ushort_t* WqTl = PCW_l;
  ushort_t* WvTh = PCW_h + NL_ * DD;      ushort_t* WvTl = PCW_l + NL_ * DD;

  // ---- precompute: transposed/split weight planes in scratch (one batched launch) ----
  tsplit3<<<dim3(24, 24, 3 * NL_), 256, 0, stream>>>(Wq, Wk, Wv,
                                                     WqTh, WqTl, WkTh, WkTl, WvTh, WvTl);
  wsplit<<<512, 256, 0, stream>>>(Wo, WoH, WoL, NL_ * DD);
  wsplit<<<1024, 256, 0, stream>>>(Wc1, W1H, nullptr, NL_ * DF);
  wsplit<<<1024, 256, 0, stream>>>(Wc2, W2H, nullptr, NL_ * DF);
  conv_w_repack<<<(CMID_ * 3 * D_ + 255) / 256, 256, 0, stream>>>(cw, WTC);

  // fused weights in ONE batched GEMM: z<NL -> MT = WkT*WqT^T(NT), z>=NL -> Wvo = Wo*WvT^T
  gemm_bf16<0, true, 2><<<144, 256, 0, stream>>>(PCA_h, PCA_l, PCW_h, PCW_l, nullptr, nullptr, nullptr,
                                                 PCC_h, PCC_l, nullptr, nullptr, nullptr, nullptr,
                                                 D_, D_, D_, (long long)DD, (long long)DD, (long long)DD, 6, 6);
  bvo_k<<<(NL_ * D_ + 255) / 256, 256, 0, stream>>>(Wo, bv, bo, BVO);

  // ---- embeddings + LN (planes only) ----
  embed_ln<<<NROWS_, 256, 0, stream>>>(ids, we, pe, te, elng, elnb, Xh, Xl);

  for (int l = 0; l < NL_; l++) {
    // XM = X * M (split in/out)
    gemm_bf16<0, true, 2><<<768, 256, 0, stream>>>(Xh, Xl, MTh + l*DD, MTl + l*DD, nullptr, nullptr, nullptr,
                                                   XMh, XMl, nullptr, nullptr, nullptr, nullptr,
                                                   D_, D_, D_, 0, 0, 0, 6, 128);
    // P = X * Wvo^T + bvo -> bf16
    gemm_bf16<0, false, 1><<<768, 256, 0, stream>>>(Xh, nullptr, WvoH + l*DD, nullptr, BVO + l*D_, nullptr, nullptr,
                                                    Pb, nullptr, nullptr, nullptr, nullptr, nullptr,
                                                    D_, D_, D_, 0, 0, 0, 6, 128);
    // scores -> circular-delay partials (batched, split)
    gemm_bf16<0, true, 3><<<512, 256, 0, stream>>>(XMh, XMl, Xh, Xl, nullptr, nullptr, nullptr,
                                                   MVP, nullptr, nullptr, nullptr, nullptr, nullptr,
                                                   L_, D_, D_, (long long)L_ * D_, (long long)L_ * D_, 0, 4, 4);
    topk_softmax<<<B_, 256, 0, stream>>>(MVP, WT, DT);
    // fused: Y = agg(P) + X, decomp -> X2 planes (distinct buffers, race-free)
    agg_decomp<<<(B_ * 8 * D_) / 256, 256, 0, stream>>>(Pb, WT, DT, Xh, Xl, X2h, X2l);
    // FFN (reads X2, residual X2, writes back to X planes)
    gemm_bf16<1, false, 1><<<3072, 256, 0, stream>>>(X2h, nullptr, W1H + l*DF, nullptr, bc1 + l*DFF_, nullptr, nullptr,
                                                     Gh, nullptr, nullptr, nullptr, nullptr, nullptr,
                                                     DFF_, D_, D_, 0, 0, 0, 24, 128);
    gemm_bf16<0, false, 0><<<768, 256, 0, stream>>>(Gh, nullptr, W2H + l*DF, nullptr, bc2 + l*D_, X2h, X2l,
                                                    Y, nullptr, nullptr, nullptr, nullptr, nullptr,
                                                    D_, DFF_, DFF_, 0, 0, 0, 6, 128);
    decomp_pl<<<(B_ * 8 * D_) / 256, 256, 0, stream>>>(Y, Xh, Xl);
  }

  // my_Layernorm + column-center, bf16 plane for conv
  ln_pl<<<NROWS_, 256, 0, stream>>>(Xh, Xl, LNo, ng, nb, 1e-5f);
  colmean_bf16<<<(B_ * D_ + 255) / 256, 256, 0, stream>>>(LNo, Sh);

  // conv1d as GEMM with fused BN+ELU+maxpool epilogue -> F
  gemm_bf16<0, false, 4><<<384, 256, 0, stream>>>(Sh, nullptr, WTC, nullptr, cb, nullptr, nullptr,
                                                  F, nullptr, bnm, bnv, bng, bnb,
                                                  CMID_, 3 * D_, D_, 0, 0, 0, 3, 128);
  lin1_k<<<dim3(LATENT_, B_), 256, 0, stream>>>(F, l1w, l1b, HP);
  ln_elu<<<B_, 64, 0, stream>>>(HP, l2g, l2b, HH);
  lin2_sig<<<(B_ * NCELLS_ + 255) / 256, 256, 0, stream>>>(HH, l2w, l2bi, out);
}

// Round 13
// 1206.143 us; speedup vs baseline: 1.1164x; 1.1164x over previous
//
#include <hip/hip_runtime.h>
#include <hip/hip_bf16.h>

#define B_ 32
#define L_ 512
#define D_ 768
#define DFF_ 3072
#define NL_ 2
#define TOPK_ 6
#define CMID_ 384
#define CLEN_ 510
#define PLEN_ 255
#define LATENT_ 32
#define NCELLS_ 2034
#define NROWS_ (B_*L_)
#define ND_ ((size_t)B_*L_*D_)

typedef unsigned short ushort_t;
typedef __attribute__((ext_vector_type(8))) short short8;
typedef __attribute__((ext_vector_type(4))) float f32x4;

typedef const __attribute__((address_space(1))) unsigned int* gp1;
typedef __attribute__((address_space(3))) unsigned int* lp3;

static __device__ __forceinline__ void gload16(const ushort_t* g, ushort_t* l) {
  __builtin_amdgcn_global_load_lds((gp1)g, (lp3)l, 16, 0, 0);
}

static __device__ __forceinline__ float geluf(float x) {
  return 0.5f * x * (1.f + erff(x * 0.70710678118654752440f));
}
static __device__ __forceinline__ float eluf(float x) {
  return x > 0.f ? x : expm1f(x);
}
static __device__ __forceinline__ ushort_t bf16rn(float f) {
  unsigned u = __builtin_bit_cast(unsigned, f);
  u = u + 0x7FFFu + ((u >> 16) & 1u);
  return (ushort_t)(u >> 16);
}
static __device__ __forceinline__ float bf16tof(ushort_t s) {
  unsigned u = ((unsigned)s) << 16;
  return __builtin_bit_cast(float, u);
}
static __device__ __forceinline__ f32x4 mfma16(short8 a, short8 b, f32x4 c) {
  return __builtin_amdgcn_mfma_f32_16x16x32_bf16(a, b, c, 0, 0, 0);
}

// ---------------- weight conversion ----------------
__global__ void wsplit(const float* __restrict__ w, ushort_t* __restrict__ hi,
                       ushort_t* __restrict__ lo, size_t n) {
  size_t stride = (size_t)gridDim.x * blockDim.x;
  for (size_t i = (size_t)blockIdx.x * blockDim.x + threadIdx.x; i < n; i += stride) {
    float v = w[i];
    ushort_t h = bf16rn(v);
    hi[i] = h;
    if (lo) lo[i] = bf16rn(v - bf16tof(h));
  }
}

// batched transpose+split over 3 matrices x NL layers (z = mat*NL + layer)
__global__ __launch_bounds__(256) void tsplit3(const float* __restrict__ w0, const float* __restrict__ w1,
                                               const float* __restrict__ w2,
                                               ushort_t* __restrict__ h0, ushort_t* __restrict__ l0p,
                                               ushort_t* __restrict__ h1, ushort_t* __restrict__ l1p,
                                               ushort_t* __restrict__ h2, ushort_t* __restrict__ l2p) {
  __shared__ float tile[32][33];
  int z = blockIdx.z;
  int m = z / NL_, l = z % NL_;
  const float* in = (m == 0) ? w0 : (m == 1 ? w1 : w2);
  ushort_t* hiT = (m == 0) ? h0 : (m == 1 ? h1 : h2);
  ushort_t* loT = (m == 0) ? l0p : (m == 1 ? l1p : l2p);
  size_t off = (size_t)l * D_ * D_;
  int bx = blockIdx.x * 32, by = blockIdx.y * 32;
  int tx = threadIdx.x & 31, ty = threadIdx.x >> 5;
#pragma unroll
  for (int i = 0; i < 32; i += 8)
    tile[ty + i][tx] = in[off + (size_t)(by + ty + i) * D_ + bx + tx];
  __syncthreads();
#pragma unroll
  for (int i = 0; i < 32; i += 8) {
    float v = tile[tx][ty + i];
    ushort_t h = bf16rn(v);
    size_t o = off + (size_t)(bx + ty + i) * D_ + by + tx;
    hiT[o] = h;
    loT[o] = bf16rn(v - bf16tof(h));
  }
}

// bvo[l,a] = bo[l,a] + sum_j Wo[l,a,j]*bv[l,j]   (batched over layers)
__global__ void bvo_k(const float* __restrict__ wo, const float* __restrict__ bv,
                      const float* __restrict__ bo, float* __restrict__ bvo) {
  int gid = blockIdx.x * 256 + threadIdx.x;
  if (gid >= NL_ * D_) return;
  int l = gid / D_, a = gid % D_;
  const float* w = wo + (size_t)l * D_ * D_ + (size_t)a * D_;
  const float* b = bv + l * D_;
  float s = bo[gid];
  for (int j = 0; j < D_; j++) s = fmaf(w[j], b[j], s);
  bvo[gid] = s;
}

// conv weight repack+convert: wt[o, j*768+i] = bf16(w[o, i, j])
__global__ void conv_w_repack(const float* __restrict__ w, ushort_t* __restrict__ wt) {
  int gid = blockIdx.x * blockDim.x + threadIdx.x;
  if (gid >= CMID_ * 3 * D_) return;
  int o = gid / (3 * D_);
  int k = gid % (3 * D_);
  int j = k / D_, i = k % D_;
  wt[gid] = bf16rn(w[((size_t)o * D_ + i) * 3 + j]);
}

// ---------------- fused embeddings + LN -> bf16 hi/lo planes only ----------------
__global__ __launch_bounds__(256) void embed_ln(const int* __restrict__ ids, const float* __restrict__ we,
                                                const float* __restrict__ pe, const float* __restrict__ te,
                                                const float* __restrict__ g, const float* __restrict__ bta,
                                                ushort_t* __restrict__ xh, ushort_t* __restrict__ xl) {
  int row = blockIdx.x;
  int tid = threadIdx.x;
  int t = row & (L_ - 1);
  int id = ids[row];
  float v[3];
#pragma unroll
  for (int dd = 0; dd < 3; dd++) {
    int c = tid + dd * 256;
    v[dd] = we[(size_t)id * D_ + c] + pe[(size_t)t * D_ + c] + te[c];
  }
  float s = v[0] + v[1] + v[2];
  float sq = v[0]*v[0] + v[1]*v[1] + v[2]*v[2];
  __shared__ float rs[256], rq[256];
  rs[tid] = s; rq[tid] = sq;
  __syncthreads();
  for (int st = 128; st > 0; st >>= 1) {
    if (tid < st) { rs[tid] += rs[tid + st]; rq[tid] += rq[tid + st]; }
    __syncthreads();
  }
  __shared__ float smu, ssc;
  if (tid == 0) {
    float mu = rs[0] * (1.f / D_);
    float var = fmaxf(rq[0] * (1.f / D_) - mu * mu, 0.f);
    smu = mu; ssc = rsqrtf(var + 1e-12f);
  }
  __syncthreads();
  float mu = smu, sc = ssc;
#pragma unroll
  for (int dd = 0; dd < 3; dd++) {
    int c = tid + dd * 256;
    size_t o = (size_t)row * D_ + c;
    float ov = (v[dd] - mu) * sc * g[c] + bta[c];
    ushort_t h = bf16rn(ov);
    xh[o] = h;
    xl[o] = bf16rn(ov - bf16tof(h));
  }
}

// ---------------- LayerNorm (head) from planes ----------------
__global__ __launch_bounds__(256) void ln_pl(const ushort_t* __restrict__ xh, const ushort_t* __restrict__ xl,
                                             float* __restrict__ out,
                                             const float* __restrict__ g, const float* __restrict__ bta,
                                             float eps) {
  int row = blockIdx.x;
  int tid = threadIdx.x;
  size_t base = (size_t)row * D_;
  float v[3];
#pragma unroll
  for (int dd = 0; dd < 3; dd++) {
    size_t o = base + tid + dd * 256;
    v[dd] = bf16tof(xh[o]) + bf16tof(xl[o]);
  }
  float s = v[0] + v[1] + v[2];
  float sq = v[0]*v[0] + v[1]*v[1] + v[2]*v[2];
  __shared__ float rs[256], rq[256];
  rs[tid] = s; rq[tid] = sq;
  __syncthreads();
  for (int st = 128; st > 0; st >>= 1) {
    if (tid < st) { rs[tid] += rs[tid + st]; rq[tid] += rq[tid + st]; }
    __syncthreads();
  }
  __shared__ float smu, ssc;
  if (tid == 0) {
    float mu = rs[0] * (1.f / D_);
    float var = fmaxf(rq[0] * (1.f / D_) - mu * mu, 0.f);
    smu = mu; ssc = rsqrtf(var + eps);
  }
  __syncthreads();
  float mu = smu, sc = ssc;
  float* o = out + base;
#pragma unroll
  for (int dd = 0; dd < 3; dd++) {
    int c = tid + dd * 256;
    o[c] = (v[dd] - mu) * sc * g[c] + bta[c];
  }
}

// ---------------- MFMA GEMM (128^2, 2-barrier), bf16-plane inputs -------------
// The proven structure (~600 TF on FFN shapes, 0 bank conflicts).
// EPI: 0 = fp32 (+plane residual), 1 = bf16, 2 = bf16 hi+lo, 3 = diag partials, 4 = conv head.
template<int ACT, bool SPLIT, int EPI>
__global__ __launch_bounds__(256) void gemm_bf16(
    const ushort_t* __restrict__ Ah, const ushort_t* __restrict__ Al,
    const ushort_t* __restrict__ Wh, const ushort_t* __restrict__ Wl,
    const float* __restrict__ bias,
    const ushort_t* __restrict__ ResH, const ushort_t* __restrict__ ResL,
    void* __restrict__ C0, void* __restrict__ C1,
    const float* __restrict__ bn_m, const float* __restrict__ bn_v,
    const float* __restrict__ bn_g, const float* __restrict__ bn_b,
    int O, int K, int lda,
    long long sA, long long sW, long long sC,
    int nbx, int nby) {
  constexpr int NP = SPLIT ? 2 : 1;
  __shared__ __align__(16) ushort_t AsH[NP][128 * 64];
  __shared__ __align__(16) ushort_t WsH[NP][128 * 64];
  __shared__ float dsum[EPI == 3 ? 512 : 1];

  int nwg = gridDim.x;
  int wg = blockIdx.x;
  {
    int qq = nwg >> 3, rr = nwg & 7;
    int xcd = wg & 7, idx = wg >> 3;
    wg = (xcd < rr ? xcd * (qq + 1) : rr * (qq + 1) + (xcd - rr) * qq) + idx;
  }
  int per_b = nbx * nby;
  int bz = wg / per_b;
  int rem = wg - bz * per_b;
  int gsz = nbx * 8;
  int grp = rem / gsz;
  int ing = rem - grp * gsz;
  int by0 = grp * 8;
  int gmx = min(8, nby - by0);
  int by = by0 + (ing % gmx);
  int bx = ing / gmx;

  const ushort_t* Ahb = Ah + (size_t)bz * sA;
  const ushort_t* Alb = SPLIT ? (Al + (size_t)bz * sA) : nullptr;
  const ushort_t* Whb = Wh + (size_t)bz * sW;
  const ushort_t* Wlb = SPLIT ? (Wl + (size_t)bz * sW) : nullptr;

  int m0 = by * 128, o0 = bx * 128;
  int tid = threadIdx.x;
  int wave = tid >> 6, lane = tid & 63;
  int wm = (wave >> 1) * 64, wn = (wave & 1) * 64;
  int lcol = lane & 15, lk = lane >> 4;

  if (EPI == 3) {
    for (int s = tid; s < 512; s += 256) dsum[s] = 0.f;
  }

  f32x4 acc[4][4] = {};

  int r8 = lane >> 3;
  int kc = (((lane & 7) ^ r8) << 3);

  const ushort_t *gA[4], *gW[4], *gAl[4], *gWl[4];
#pragma unroll
  for (int i = 0; i < 4; i++) {
    int ch = wave * 4 + i;
    int row = ch * 8 + r8;
    size_t oa = (size_t)(m0 + row) * lda + kc;
    size_t ow = (size_t)(o0 + row) * K + kc;
    gA[i] = Ahb + oa; gW[i] = Whb + ow;
    if (SPLIT) { gAl[i] = Alb + oa; gWl[i] = Wlb + ow; }
  }

  for (int k0 = 0; k0 < K; k0 += 64) {
#pragma unroll
    for (int i = 0; i < 4; i++) {
      int ch = wave * 4 + i;
      gload16(gA[i], &AsH[0][ch * 512]); gA[i] += 64;
      gload16(gW[i], &WsH[0][ch * 512]); gW[i] += 64;
      if (SPLIT) {
        gload16(gAl[i], &AsH[1][ch * 512]); gAl[i] += 64;
        gload16(gWl[i], &WsH[1][ch * 512]); gWl[i] += 64;
      }
    }
    __syncthreads();
#pragma unroll
    for (int kk = 0; kk < 2; kk++) {
      int c = kk * 4 + lk;
      short8 ah[4], bh[4], al[4], bl[4];
#pragma unroll
      for (int i = 0; i < 4; i++) {
        int r = wm + i * 16 + lcol;
        int so = r * 64 + ((c ^ (r & 7)) << 3);
        ah[i] = *(const short8*)&AsH[0][so];
        if (SPLIT) al[i] = *(const short8*)&AsH[1][so];
      }
#pragma unroll
      for (int j = 0; j < 4; j++) {
        int r = wn + j * 16 + lcol;
        int so = r * 64 + ((c ^ (r & 7)) << 3);
        bh[j] = *(const short8*)&WsH[0][so];
        if (SPLIT) bl[j] = *(const short8*)&WsH[1][so];
      }
#pragma unroll
      for (int i = 0; i < 4; i++)
#pragma unroll
        for (int j = 0; j < 4; j++) {
          if (SPLIT) {
            acc[i][j] = mfma16(ah[i], bl[j], acc[i][j]);
            acc[i][j] = mfma16(al[i], bh[j], acc[i][j]);
          }
          acc[i][j] = mfma16(ah[i], bh[j], acc[i][j]);
        }
    }
    __syncthreads();
  }

  if (EPI == 3) {
    float pre[7][4] = {};
#pragma unroll
    for (int i = 0; i < 4; i++)
#pragma unroll
      for (int j = 0; j < 4; j++)
#pragma unroll
        for (int r = 0; r < 4; r++)
          pre[i - j + 3][r] += acc[i][j][r];
    int base = (m0 + wm + lk * 4) - (o0 + wn + lcol);
#pragma unroll
    for (int g = 0; g < 7; g++)
#pragma unroll
      for (int r = 0; r < 4; r++)
        atomicAdd(&dsum[(base + 16 * (g - 3) + r) & (L_ - 1)], pre[g][r]);
    __syncthreads();
    float* mvp = (float*)C0;
    int blk = by * nbx + bx;
    for (int s = tid; s < 512; s += 256)
      mvp[((size_t)bz * 16 + blk) * 512 + s] = dsum[s] * (1.f / D_);
  } else if (EPI == 4) {
#pragma unroll
    for (int j = 0; j < 4; j++) {
      int col = o0 + wn + j * 16 + lcol;
      float cbias = bias[col];
      float sc = rsqrtf(bn_v[col] + 1e-5f) * bn_g[col];
      float shf = bn_b[col] - bn_m[col] * sc;
#pragma unroll
      for (int i = 0; i < 4; i++) {
        int rowb = m0 + wm + i * 16 + lk * 4;
        int t = rowb & (L_ - 1);
        int b = rowb >> 9;
#pragma unroll
        for (int p = 0; p < 2; p++) {
          int tt = t + p * 2;
          if (tt >= CLEN_) continue;
          float v0 = eluf((acc[i][j][p * 2]     + cbias) * sc + shf);
          float v1 = eluf((acc[i][j][p * 2 + 1] + cbias) * sc + shf);
          ((float*)C0)[((size_t)b * CMID_ + col) * PLEN_ + (tt >> 1)] = fmaxf(v0, v1);
        }
      }
    }
  } else {
#pragma unroll
    for (int i = 0; i < 4; i++)
#pragma unroll
      for (int j = 0; j < 4; j++) {
        int col = o0 + wn + j * 16 + lcol;
        float bv = bias ? bias[col] : 0.f;
        int rowb = m0 + wm + i * 16 + lk * 4;
#pragma unroll
        for (int r = 0; r < 4; r++) {
          float v = acc[i][j][r] + bv;
          if (ACT == 1) v = geluf(v);
          size_t off = (size_t)bz * sC + (size_t)(rowb + r) * O + col;
          if (EPI == 0) {
            if (ResH) v += bf16tof(ResH[off]) + bf16tof(ResL[off]);
            ((float*)C0)[off] = v;
          }
          if (EPI == 1) ((ushort_t*)C0)[off] = bf16rn(v);
          if (EPI == 2) {
            ushort_t h = bf16rn(v);
            ((ushort_t*)C0)[off] = h;
            ((ushort_t*)C1)[off] = bf16rn(v - bf16tof(h));
          }
        }
      }
  }
}

// ---------------- top-k(6) + softmax over delays (sums 16 partials) ----------------
__global__ __launch_bounds__(256) void topk_softmax(const float* __restrict__ mvp,
                                                    float* __restrict__ wout, int* __restrict__ dout) {
  int b = blockIdx.x, tid = threadIdx.x;
  __shared__ float vals[L_];
  __shared__ float rv[256];
  __shared__ int ri[256];
  __shared__ float wsel[TOPK_];
  __shared__ int dsel[TOPK_];
  float s0 = 0.f, s1 = 0.f;
  for (int p = 0; p < 16; p++) {
    const float* pp = mvp + ((size_t)b * 16 + p) * L_;
    s0 += pp[tid]; s1 += pp[tid + 256];
  }
  vals[tid] = s0; vals[tid + 256] = s1;
  for (int kk = 0; kk < TOPK_; kk++) {
    __syncthreads();
    float v0 = vals[tid], v1 = vals[tid + 256];
    float bvv = v0; int bi = tid;
    if (v1 > v0) { bvv = v1; bi = tid + 256; }
    rv[tid] = bvv; ri[tid] = bi;
    __syncthreads();
    for (int st = 128; st > 0; st >>= 1) {
      if (tid < st) {
        float ov = rv[tid + st]; int oi = ri[tid + st];
        if (ov > rv[tid] || (ov == rv[tid] && oi < ri[tid])) { rv[tid] = ov; ri[tid] = oi; }
      }
      __syncthreads();
    }
    if (tid == 0) { wsel[kk] = rv[0]; dsel[kk] = ri[0]; vals[ri[0]] = -INFINITY; }
  }
  __syncthreads();
  if (tid == 0) {
    float mx = wsel[0];
    for (int i = 1; i < TOPK_; i++) mx = fmaxf(mx, wsel[i]);
    float e[TOPK_]; float sum = 0.f;
    for (int i = 0; i < TOPK_; i++) { e[i] = expf(wsel[i] - mx); sum += e[i]; }
    for (int i = 0; i < TOPK_; i++) { wout[b * TOPK_ + i] = e[i] / sum; dout[b * TOPK_ + i] = dsel[i]; }
  }
}

// y[b,t,d] = sum_k w[b,k] * P[b,(t+delay[b,k])%L,d] + (xh+xl)[b,t,d]
__global__ __launch_bounds__(256) void agg_res(const ushort_t* __restrict__ P, const float* __restrict__ w,
                                               const int* __restrict__ dly,
                                               const ushort_t* __restrict__ xh, const ushort_t* __restrict__ xl,
                                               float* __restrict__ y) {
  int blr = blockIdx.x;      // b*L + t
  int b = blr >> 9, t = blr & 511;
  int tid = threadIdx.x;
  __shared__ float ww[TOPK_];
  __shared__ int rr[TOPK_];
  if (tid < TOPK_) { ww[tid] = w[b * TOPK_ + tid]; rr[tid] = (t + dly[b * TOPK_ + tid]) & (L_ - 1); }
  __syncthreads();
  const ushort_t* pb = P + (size_t)b * L_ * D_;
#pragma unroll
  for (int dd = 0; dd < 3; dd++) {
    int d = tid + dd * 256;
    size_t o = (size_t)blr * D_ + d;
    float s = bf16tof(xh[o]) + bf16tof(xl[o]);
#pragma unroll
    for (int kk = 0; kk < TOPK_; kk++)
      s = fmaf(ww[kk], bf16tof(pb[(size_t)rr[kk] * D_ + d]), s);
    y[o] = s;
  }
}

// race-free decomp: reads fp32 sum S, writes bf16 hi/lo planes
__global__ void decomp_pl(const float* __restrict__ s,
                          ushort_t* __restrict__ xh, ushort_t* __restrict__ xl) {
  int gid = blockIdx.x * blockDim.x + threadIdx.x;   // B*8*D
  if (gid >= B_ * 8 * D_) return;
  int d = gid % D_;
  int chunk = (gid / D_) & 7;
  int b = gid / (D_ * 8);
  size_t base = (size_t)b * L_ * D_ + d;
  int t0 = chunk * 64;
  float wsum = 0.f;
  for (int u = t0 - 12; u <= t0 + 12; u++) {
    int uc = u < 0 ? 0 : (u > L_ - 1 ? L_ - 1 : u);
    wsum += s[base + (size_t)uc * D_];
  }
  for (int t = t0; t < t0 + 64; t++) {
    size_t o = base + (size_t)t * D_;
    float v = s[o] - wsum * (1.f / 25.f);
    ushort_t h = bf16rn(v);
    xh[o] = h;
    xl[o] = bf16rn(v - bf16tof(h));
    int ua = t + 13 > L_ - 1 ? L_ - 1 : t + 13;
    int ur = t - 12 < 0 ? 0 : t - 12;
    wsum += s[base + (size_t)ua * D_] - s[base + (size_t)ur * D_];
  }
}

// x[b,:,d] -= mean_t; write bf16 plane only
__global__ void colmean_bf16(const float* __restrict__ x, ushort_t* __restrict__ sh) {
  int gid = blockIdx.x * blockDim.x + threadIdx.x;   // B*D
  if (gid >= B_ * D_) return;
  int d = gid % D_, b = gid / D_;
  const float* col = x + (size_t)b * L_ * D_ + d;
  ushort_t* oc = sh + (size_t)b * L_ * D_ + d;
  float s = 0.f;
  for (int t = 0; t < L_; t++) s += col[(size_t)t * D_];
  float mu = s * (1.f / L_);
  for (int t = 0; t < L_; t++) oc[(size_t)t * D_] = bf16rn(col[(size_t)t * D_] - mu);
}

__global__ __launch_bounds__(256) void lin1_k(const float* __restrict__ f, const float* __restrict__ w,
                                              const float* __restrict__ bias, float* __restrict__ out) {
  int o = blockIdx.x, b = blockIdx.y;
  int tid = threadIdx.x;
  const float4* fr = (const float4*)(f + (size_t)b * (CMID_ * PLEN_));
  const float4* wr = (const float4*)(w + (size_t)o * (CMID_ * PLEN_));
  const int n4 = CMID_ * PLEN_ / 4;
  float s = 0.f;
  for (int i = tid; i < n4; i += 256) {
    float4 a = fr[i], ww = wr[i];
    s += a.x * ww.x + a.y * ww.y + a.z * ww.z + a.w * ww.w;
  }
  __shared__ float red[256];
  red[tid] = s;
  __syncthreads();
  for (int st = 128; st > 0; st >>= 1) {
    if (tid < st) red[tid] += red[tid + st];
    __syncthreads();
  }
  if (tid == 0) out[b * LATENT_ + o] = red[0] + bias[o];
}

__global__ void ln_elu(const float* __restrict__ hp, const float* __restrict__ g,
                       const float* __restrict__ bb, float* __restrict__ h) {
  int b = blockIdx.x;
  int tid = threadIdx.x;   // 64
  __shared__ float v[LATENT_];
  __shared__ float mu_s, sc_s;
  if (tid < LATENT_) v[tid] = hp[b * LATENT_ + tid];
  __syncthreads();
  if (tid == 0) {
    float s = 0.f, sq = 0.f;
    for (int i = 0; i < LATENT_; i++) { s += v[i]; sq += v[i] * v[i]; }
    float mu = s * (1.f / LATENT_);
    float var = fmaxf(sq * (1.f / LATENT_) - mu * mu, 0.f);
    mu_s = mu; sc_s = rsqrtf(var + 1e-5f);
  }
  __syncthreads();
  if (tid < LATENT_) h[b * LATENT_ + tid] = eluf((v[tid] - mu_s) * sc_s * g[tid] + bb[tid]);
}

__global__ void lin2_sig(const float* __restrict__ h, const float* __restrict__ w,
                         const float* __restrict__ bias, float* __restrict__ out) {
  int gid = blockIdx.x * blockDim.x + threadIdx.x;
  if (gid >= B_ * NCELLS_) return;
  int b = gid / NCELLS_, c = gid % NCELLS_;
  const float* hr = h + b * LATENT_;
  const float* wr = w + (size_t)c * LATENT_;
  float s = bias[c];
  for (int j = 0; j < LATENT_; j++) s = fmaf(hr[j], wr[j], s);
  out[gid] = 1.f / (1.f + expf(-s));
}

extern "C" void kernel_launch(void* const* d_in, const int* in_sizes, int n_in,
                              void* d_out, int out_size, void* d_ws, size_t ws_size,
                              hipStream_t stream) {
  const int*   ids  = (const int*)  d_in[0];
  const float* we   = (const float*)d_in[1];
  const float* pe   = (const float*)d_in[2];
  const float* te   = (const float*)d_in[3];
  const float* elng = (const float*)d_in[4];
  const float* elnb = (const float*)d_in[5];
  const float* Wq   = (const float*)d_in[6];
  const float* bq   = (const float*)d_in[7];   (void)bq;  // drops out (shift-invariance)
  const float* Wk   = (const float*)d_in[8];
  const float* bk   = (const float*)d_in[9];   (void)bk;  // drops out
  const float* Wv   = (const float*)d_in[10];
  const float* bv   = (const float*)d_in[11];
  const float* Wo   = (const float*)d_in[12];
  const float* bo   = (const float*)d_in[13];
  const float* Wc1  = (const float*)d_in[14];
  const float* bc1  = (const float*)d_in[15];
  const float* Wc2  = (const float*)d_in[16];
  const float* bc2  = (const float*)d_in[17];
  const float* ng   = (const float*)d_in[18];
  const float* nb   = (const float*)d_in[19];
  const float* cw   = (const float*)d_in[20];
  const float* cb   = (const float*)d_in[21];
  const float* bng  = (const float*)d_in[22];
  const float* bnb  = (const float*)d_in[23];
  const float* bnm  = (const float*)d_in[24];
  const float* bnv  = (const float*)d_in[25];
  const float* l1w  = (const float*)d_in[26];
  const float* l1b  = (const float*)d_in[27];
  const float* l2g  = (const float*)d_in[28];
  const float* l2b  = (const float*)d_in[29];
  const float* l2w  = (const float*)d_in[30];
  const float* l2bi = (const float*)d_in[31];
  float* out = (float*)d_out;

  // ---- workspace carve-up ----
  char* wp = (char*)d_ws;
  auto alloc = [&](size_t bytes) { char* p = wp; wp += (bytes + 255) & ~(size_t)255; return p; };
  ushort_t* Xh  = (ushort_t*)alloc(ND_ * 2);
  ushort_t* Xl  = (ushort_t*)alloc(ND_ * 2);
  ushort_t* R1  = (ushort_t*)alloc(ND_ * 2 * 4);   // XMh|XMl ; precompute scratch ; Gh ; F(head)
  char*     PvB = (char*)    alloc(ND_ * 4);       // P bf16 ; head: LN fp32 output
  float*    Y   = (float*)   alloc(ND_ * 4);       // residual sums (fp32)
  float*    MVP = (float*)   alloc((size_t)B_ * 16 * L_ * 4);
  float*    WT  = (float*)   alloc(B_ * TOPK_ * 4);
  int*      DT  = (int*)     alloc(B_ * TOPK_ * 4);
  float*    HP  = (float*)   alloc(B_ * LATENT_ * 4);
  float*    HH  = (float*)   alloc(B_ * LATENT_ * 4);
  const size_t DD = (size_t)D_ * D_, DF = (size_t)DFF_ * D_;
  // persistent fused-weight block: C-hi = [MTh l0,l1 | WvoH l0,l1], C-lo = [MTl l0,l1 | (junk)]
  ushort_t* PCC_h = (ushort_t*)alloc(4 * DD * 2);
  ushort_t* PCC_l = (ushort_t*)alloc(4 * DD * 2);
  float*    BVO  = (float*)   alloc(NL_ * D_ * 4);   // Wo*bv + bo
  ushort_t* W1H  = (ushort_t*)alloc(NL_ * DF * 2);
  ushort_t* W2H  = (ushort_t*)alloc(NL_ * DF * 2);
  ushort_t* WTC  = (ushort_t*)alloc((size_t)CMID_ * 3 * D_ * 2);

  ushort_t* MTh  = PCC_h;                // + l*DD
  ushort_t* MTl  = PCC_l;
  ushort_t* WvoH = PCC_h + NL_ * DD;

  ushort_t* XMh = R1;
  ushort_t* XMl = R1 + ND_;
  ushort_t* Gh  = R1;          // FFN mid, overlays whole R1
  float*    F   = (float*)R1;  // head pooled features
  ushort_t* Pb  = (ushort_t*)PvB;   // P bf16
  float*    LNo = (float*)PvB;      // head LN output (P dead)
  ushort_t* Sh  = Xh;               // head bf16 plane (X planes dead at head)

  // precompute scratch planes (overlay R1 — dead until the layer loop).
  ushort_t* SC = R1;
  ushort_t* PCA_h = SC;                   // 4*DD
  ushort_t* PCA_l = SC + 4 * DD;
  ushort_t* PCW_h = SC + 8 * DD;
  ushort_t* PCW_l = SC + 12 * DD;
  ushort_t* WkTh = PCA_h;                 ushort_t* WkTl = PCA_l;
  ushort_t* WoH  = PCA_h + NL_ * DD;      ushort_t* WoL  = PCA_l + NL_ * DD;
  ushort_t* WqTh = PCW_h;                 ushort_t* WqTl = PCW_l;
  ushort_t* WvTh = PCW_h + NL_ * DD;      ushort_t* WvTl = PCW_l + NL_ * DD;

  // ---- precompute: transposed/split weight planes in scratch (one batched launch) ----
  tsplit3<<<dim3(24, 24, 3 * NL_), 256, 0, stream>>>(Wq, Wk, Wv,
                                                     WqTh, WqTl, WkTh, WkTl, WvTh, WvTl);
  wsplit<<<512, 256, 0, stream>>>(Wo, WoH, WoL, NL_ * DD);
  wsplit<<<1024, 256, 0, stream>>>(Wc1, W1H, nullptr, NL_ * DF);
  wsplit<<<1024, 256, 0, stream>>>(Wc2, W2H, nullptr, NL_ * DF);
  conv_w_repack<<<(CMID_ * 3 * D_ + 255) / 256, 256, 0, stream>>>(cw, WTC);

  // fused weights in ONE batched GEMM: z<NL -> MT = WkT*WqT^T(NT), z>=NL -> Wvo = Wo*WvT^T
  gemm_bf16<0, true, 2><<<144, 256, 0, stream>>>(PCA_h, PCA_l, PCW_h, PCW_l, nullptr, nullptr, nullptr,
                                                 PCC_h, PCC_l, nullptr, nullptr, nullptr, nullptr,
                                                 D_, D_, D_, (long long)DD, (long long)DD, (long long)DD, 6, 6);
  bvo_k<<<(NL_ * D_ + 255) / 256, 256, 0, stream>>>(Wo, bv, bo, BVO);

  // ---- embeddings + LN (planes only) ----
  embed_ln<<<NROWS_, 256, 0, stream>>>(ids, we, pe, te, elng, elnb, Xh, Xl);

  for (int l = 0; l < NL_; l++) {
    // XM = X * M (split in/out)
    gemm_bf16<0, true, 2><<<768, 256, 0, stream>>>(Xh, Xl, MTh + l*DD, MTl + l*DD, nullptr, nullptr, nullptr,
                                                   XMh, XMl, nullptr, nullptr, nullptr, nullptr,
                                                   D_, D_, D_, 0, 0, 0, 6, 128);
    // P = X * Wvo^T + bvo -> bf16
    gemm_bf16<0, false, 1><<<768, 256, 0, stream>>>(Xh, nullptr, WvoH + l*DD, nullptr, BVO + l*D_, nullptr, nullptr,
                                                    Pb, nullptr, nullptr, nullptr, nullptr, nullptr,
                                                    D_, D_, D_, 0, 0, 0, 6, 128);
    // scores -> circular-delay partials (batched, split)
    gemm_bf16<0, true, 3><<<512, 256, 0, stream>>>(XMh, XMl, Xh, Xl, nullptr, nullptr, nullptr,
                                                   MVP, nullptr, nullptr, nullptr, nullptr, nullptr,
                                                   L_, D_, D_, (long long)L_ * D_, (long long)L_ * D_, 0, 4, 4);
    topk_softmax<<<B_, 256, 0, stream>>>(MVP, WT, DT);
    // Y = agg(P) + X  (planes in, fp32 out) then decomp -> planes
    agg_res<<<NROWS_, 256, 0, stream>>>(Pb, WT, DT, Xh, Xl, Y);
    decomp_pl<<<(B_ * 8 * D_) / 256, 256, 0, stream>>>(Y, Xh, Xl);
    // FFN
    gemm_bf16<1, false, 1><<<3072, 256, 0, stream>>>(Xh, nullptr, W1H + l*DF, nullptr, bc1 + l*DFF_, nullptr, nullptr,
                                                     Gh, nullptr, nullptr, nullptr, nullptr, nullptr,
                                                     DFF_, D_, D_, 0, 0, 0, 24, 128);
    gemm_bf16<0, false, 0><<<768, 256, 0, stream>>>(Gh, nullptr, W2H + l*DF, nullptr, bc2 + l*D_, Xh, Xl,
                                                    Y, nullptr, nullptr, nullptr, nullptr, nullptr,
                                                    D_, DFF_, DFF_, 0, 0, 0, 6, 128);
    decomp_pl<<<(B_ * 8 * D_) / 256, 256, 0, stream>>>(Y, Xh, Xl);
  }

  // my_Layernorm + column-center, bf16 plane for conv
  ln_pl<<<NROWS_, 256, 0, stream>>>(Xh, Xl, LNo, ng, nb, 1e-5f);
  colmean_bf16<<<(B_ * D_ + 255) / 256, 256, 0, stream>>>(LNo, Sh);

  // conv1d as GEMM with fused BN+ELU+maxpool epilogue -> F
  gemm_bf16<0, false, 4><<<384, 256, 0, stream>>>(Sh, nullptr, WTC, nullptr, cb, nullptr, nullptr,
                                                  F, nullptr, bnm, bnv, bng, bnb,
                                                  CMID_, 3 * D_, D_, 0, 0, 0, 3, 128);
  lin1_k<<<dim3(LATENT_, B_), 256, 0, stream>>>(F, l1w, l1b, HP);
  ln_elu<<<B_, 64, 0, stream>>>(HP, l2g, l2b, HH);
  lin2_sig<<<(B_ * NCELLS_ + 255) / 256, 256, 0, stream>>>(HH, l2w, l2bi, out);
}